// Round 8
// baseline (1563.244 us; speedup 1.0000x reference)
//
#include <hip/hip_runtime.h>
#include <math.h>

#define NLOC 20000
#define MNB  30

// ---------------------------------------------------------------------------
// prep: tiled transpose response (64, N) -> respT (N, 64), both sides
// coalesced; also zero the scalar output (harness poisons d_out).
// ---------------------------------------------------------------------------
__global__ __launch_bounds__(256)
void prep_transpose(const float* __restrict__ resp,
                    float* __restrict__ respT,
                    float* __restrict__ out) {
    __shared__ float tile[64][65];                 // +1 pad: conflict-free both ways
    const int j0 = blockIdx.x * 64;
    const int tx = threadIdx.x & 63;
    const int ty = threadIdx.x >> 6;               // 0..3
    if (blockIdx.x == 0 && threadIdx.x == 0) out[0] = 0.0f;

#pragma unroll
    for (int rr = 0; rr < 16; ++rr) {              // rows r = 4*rr + ty
        int r = rr * 4 + ty;
        int j = j0 + tx;
        tile[r][tx] = (j < NLOC) ? resp[r * NLOC + j] : 0.0f;   // coalesced read
    }
    __syncthreads();
#pragma unroll
    for (int jj = 0; jj < 16; ++jj) {              // cols j = j0 + 4*jj + ty
        int j = j0 + jj * 4 + ty;
        if (j < NLOC) respT[j * 64 + tx] = tile[tx][jj * 4 + ty];  // coalesced write
    }
}

// wave-uniform broadcast: lane l's value -> SGPR (consumed as scalar operand)
__device__ __forceinline__ float rl(float v, int l) {
    return __uint_as_float(__builtin_amdgcn_readlane(__float_as_uint(v), l));
}

// ---------------------------------------------------------------------------
// main: ONE BLOCK (2 waves, 128 thr) per location. Lane = row r of the 64x64
// system; wave wv owns columns c with (c&1)==wv, stored A[32] per lane.
// Rationale: rounds 2/3/4/7 proved hipcc never keeps a 64-deep unrolled
// register array in arch VGPRs (grants 60-92, shunting overflow to AGPR
// copies ~2.5x inst bloat, or scratch 95-503MB). A[32]+temps ~55 regs fits
// every cap ever granted. Cross-wave traffic: double-buffered LDS column
// (chol) / partial-sum vector (solve), one barrier per step.
// ---------------------------------------------------------------------------
__global__ __launch_bounds__(128, 4)
void vecchia_main(const float* __restrict__ locs,
                  const float* __restrict__ respT,
                  const int*   __restrict__ cs,
                  const float* __restrict__ theta,
                  float* __restrict__ out) {
    const int wv   = threadIdx.x >> 6;         // 0/1, wave-uniform
    const int lane = threadIdx.x & 63;         // row r
    const int i    = blockIdx.x;               // location

    __shared__ float col_buf[2][64];           // chol column k (dbuf by k&1)
    __shared__ float sacc_buf[2][64];          // solve partial sums (dbuf by j&1)
    __shared__ float part_ld[2], part_q[2];

    const float th0 = theta[0], th1 = theta[1], th2 = theta[2];
    const float th3 = theta[3], th4 = theta[4], th5 = theta[5];

    float y_own = respT[i * 64 + lane];        // own response (solve RHS)

    // ---- per-location scale -> nug_mean, sigma (uniform) ----------------
    float logscal = 0.0f;
    {
        int n1 = cs[1 * MNB];
        float ax = locs[2] - locs[2 * n1], ay = locs[3] - locs[2 * n1 + 1];
        float d0 = sqrtf(ax * ax + ay * ay);
        int n5 = cs[5 * MNB];
        float bx = locs[10] - locs[2 * n5], by = locs[11] - locs[2 * n5 + 1];
        float d4 = sqrtf(bx * bx + by * by);
        if (i > 0) {
            int ni = cs[i * MNB];
            float cx = locs[2 * i] - locs[2 * ni];
            float cy = locs[2 * i + 1] - locs[2 * ni + 1];
            float di = sqrtf(cx * cx + cy * cy);
            float s0 = d0 * d0 / d4;
            logscal = __logf(di / s0);
        }
    }
    float nug = __expf(logscal * th1 + th0);
    nug = fmaxf(nug - 1e-5f, 0.0f) + 1e-5f;
    const float inv_nug = 1.0f / nug;
    float sig = __expf(logscal * th4 + th3);
    const float sig2 = sig * sig;
    float len = __expf(th5) * 1.7320508075688772f;   // * sqrt(2*1.5)
    const float inv_len2 = 1.0f / (len * len);
    const float et2 = __expf(th2);

    // ---- gram (outer-product; this wave's 32 columns only) --------------
    float A[32];
#pragma unroll
    for (int cc = 0; cc < 32; ++cc) A[cc] = 0.0f;
    float sq_own = 0.0f;
#pragma unroll
    for (int j = 0; j < 30; ++j) {
        int cj = cs[i * MNB + j];                      // wave-uniform
        float scl = __expf(-0.5f * (float)(j + 1) * et2);
        float xj = 0.0f;
        if (cj >= 0) xj = respT[cj * 64 + lane] * scl; // coalesced 256B row
        sq_own = fmaf(xj, xj, sq_own);                 // identical in both waves
#pragma unroll
        for (int cc = 0; cc < 32; ++cc)
            A[cc] = fmaf(xj, rl(xj, 2 * cc + wv), A[cc]);
    }

    // ---- transform: A = (lin + sigma^2*matern)/nug + I ------------------
    const float mc = 1.7320508075688772f;  // sqrt(3)
#pragma unroll
    for (int cc = 0; cc < 32; ++cc) {
        int c = 2 * cc + wv;
        float acc = A[cc];
        float dc = rl(sq_own, c);
        float d2 = fmaxf((sq_own + dc - 2.0f * acc) * inv_len2, 1e-12f);
        float d  = sqrtf(d2);
        float t  = mc * d;
        float mat = (1.0f + t) * __expf(-t);
        A[cc] = (acc + sig2 * mat) * inv_nug + ((c == lane) ? 1.0f : 0.0f);
    }

    // ---- Cholesky: owner wave publishes column k via LDS, both update ---
    float logdet_acc = 0.0f;
    float my_dinv = 0.0f;
#pragma unroll
    for (int k = 0; k < 64; ++k) {
        if (wv == (k & 1)) {                           // owner wave
            float colv = A[k >> 1];
            float p   = rl(colv, k);                   // pivot (uniform)
            float inv = __frsqrt_rn(p);
            logdet_acc += __logf(p);
            float myL = colv * inv;                    // L[r][k]
            A[k >> 1] = myL;
            my_dinv = (lane == k) ? inv : my_dinv;
            col_buf[k & 1][lane] = myL;                // publish column
        }
        __syncthreads();
        float lk = col_buf[k & 1][lane];               // L[r][k], both waves
#pragma unroll
        for (int cc = 0; cc < 32; ++cc) {
            const int ce = 2 * cc;                     // col for wv=0
            if (ce > k) {
                A[cc] = fmaf(-lk, rl(lk, ce + wv), A[cc]);
            } else if (ce == k) {                      // boundary: wv=1 col only
                if (wv) A[cc] = fmaf(-lk, rl(lk, ce + 1), A[cc]);
            }
        }
    }

    // ---- forward solve L y~ = y (alternating ownership by j&1) ----------
    float sacc = 0.0f;                                 // sum_{j' in my parity} L[r][j'] y~[j']
    float q = 0.0f;
#pragma unroll
    for (int j = 0; j < 64; ++j) {
        if (wv != (j & 1)) sacc_buf[j & 1][lane] = sacc;   // non-owner publishes
        __syncthreads();
        if (wv == (j & 1)) {                               // owner computes y~[j]
            float sl = sacc_buf[j & 1][j];                 // other parity's partial @ row j
            float t  = (y_own - sacc - sl) * my_dinv;      // lane j holds y~[j]
            float yj = rl(t, j);                           // uniform
            q    = fmaf(yj, yj, q);
            sacc = fmaf(A[j >> 1], yj, sacc);              // L[r][j] * y~[j]
        }
    }

    // ---- combine halves, log-likelihood ---------------------------------
    if (lane == 0) { part_ld[wv] = logdet_acc; part_q[wv] = q; }
    __syncthreads();
    if (threadIdx.x == 0) {
        float logdet = 0.5f * (part_ld[0] + part_ld[1]);
        float qq     = part_q[0] + part_q[1];
        const float alpha      = 2.0625f;                  // 1/16 + 2 (NUG_MULT=4)
        const float alpha_post = 34.0625f;                 // alpha + n/2
        float beta      = nug * (alpha - 1.0f);
        float beta_post = fmaf(0.5f, qq, beta);
        float loglik = -logdet + alpha * __logf(beta) - alpha_post * __logf(beta_post)
                       + lgammaf(alpha_post) - lgammaf(alpha);
        atomicAdd(out, -loglik * (1.0f / (float)NLOC));
    }
}

// ---------------------------------------------------------------------------
extern "C" void kernel_launch(void* const* d_in, const int* in_sizes, int n_in,
                              void* d_out, int out_size, void* d_ws, size_t ws_size,
                              hipStream_t stream) {
    const float* locs  = (const float*)d_in[0];
    const float* resp  = (const float*)d_in[1];
    const int*   cset  = (const int*)d_in[2];
    const float* theta = (const float*)d_in[3];
    float* out   = (float*)d_out;
    float* respT = (float*)d_ws;                      // 20000*64*4 = 5.12 MB

    prep_transpose<<<(NLOC + 63) / 64, 256, 0, stream>>>(resp, respT, out);
    vecchia_main<<<NLOC, 128, 0, stream>>>(locs, respT, cset, theta, out);
}

// Round 11
// 622.229 us; speedup vs baseline: 2.5123x; 2.5123x over previous
//
#include <hip/hip_runtime.h>
#include <math.h>

#define NLOC 20000
#define NREP 64
#define MNB  30

// ---------------------------------------------------------------------------
// prep: tiled transpose response (64, N) -> respT (N, 64), both sides
// coalesced; also zero the scalar output (harness poisons d_out).
// ---------------------------------------------------------------------------
__global__ __launch_bounds__(256)
void prep_transpose(const float* __restrict__ resp,
                    float* __restrict__ respT,
                    float* __restrict__ out) {
    __shared__ float tile[64][65];                 // +1 pad: conflict-free both ways
    const int j0 = blockIdx.x * 64;
    const int tx = threadIdx.x & 63;
    const int ty = threadIdx.x >> 6;               // 0..3
    if (blockIdx.x == 0 && threadIdx.x == 0) out[0] = 0.0f;

#pragma unroll
    for (int rr = 0; rr < 16; ++rr) {              // rows r = 4*rr + ty
        int r = rr * 4 + ty;
        int j = j0 + tx;
        tile[r][tx] = (j < NLOC) ? resp[r * NLOC + j] : 0.0f;   // coalesced read
    }
    __syncthreads();
#pragma unroll
    for (int jj = 0; jj < 16; ++jj) {              // cols j = j0 + 4*jj + ty
        int j = j0 + jj * 4 + ty;
        if (j < NLOC) respT[j * 64 + tx] = tile[tx][jj * 4 + ty];  // coalesced write
    }
}

// wave-uniform broadcast: lane l's value -> SGPR (consumed as scalar FMA operand)
__device__ __forceinline__ float rl(float v, int l) {
    return __uint_as_float(__builtin_amdgcn_readlane(__float_as_uint(v), l));
}

// ---------------------------------------------------------------------------
// main: one wave per location, lane = rep. Row of the 64x64 G in 64 VGPRs.
// SINGLE-VARIABLE A/B vs round 4 (478us): only change is launch_bounds
// min-waves 3 -> 1. Evidence: allocator VGPR grant tracks the min-waves
// hint monotonically (min4->64, min3->84, min2->92; demand ~110), shunting
// overflow to AGPR copies (~2.5x inst tax) or scratch. min=1 gives the
// allocator a 512-reg budget; if it finally grants >=110 arch VGPRs the
// AGPR tax disappears.
// ---------------------------------------------------------------------------
__global__ __launch_bounds__(256, 1)
void vecchia_main(const float* __restrict__ locs,
                  const float* __restrict__ respT,
                  const int*   __restrict__ cs,
                  const float* __restrict__ theta,
                  float* __restrict__ out) {
    const int wave = threadIdx.x >> 6;
    const int lane = threadIdx.x & 63;
    const int i    = blockIdx.x * 4 + wave;    // location, wave-uniform

    __shared__ float sh_part[4];

    const float th0 = theta[0], th1 = theta[1], th2 = theta[2];
    const float th3 = theta[3], th4 = theta[4], th5 = theta[5];

    // prefetch own y for the solve (hides latency under gram)
    float y_own = respT[i * 64 + lane];

    // ---- per-location scale -> nug_mean, sigma --------------------------
    float logscal = 0.0f;
    {
        int n1 = cs[1 * MNB];
        float ax = locs[2] - locs[2 * n1], ay = locs[3] - locs[2 * n1 + 1];
        float d0 = sqrtf(ax * ax + ay * ay);
        int n5 = cs[5 * MNB];
        float bx = locs[10] - locs[2 * n5], by = locs[11] - locs[2 * n5 + 1];
        float d4 = sqrtf(bx * bx + by * by);
        if (i > 0) {
            int ni = cs[i * MNB];
            float cx = locs[2 * i] - locs[2 * ni];
            float cy = locs[2 * i + 1] - locs[2 * ni + 1];
            float di = sqrtf(cx * cx + cy * cy);
            float s0 = d0 * d0 / d4;
            logscal = __logf(di / s0);
        }
    }
    float nug = __expf(logscal * th1 + th0);
    nug = fmaxf(nug - 1e-5f, 0.0f) + 1e-5f;
    const float inv_nug = 1.0f / nug;
    float sig = __expf(logscal * th4 + th3);
    const float sig2 = sig * sig;
    float len = __expf(th5) * 1.7320508075688772f;   // * sqrt(2*1.5)
    const float inv_len2 = 1.0f / (len * len);
    const float et2 = __expf(th2);

    // ---- gram in outer-product order: one xs element live at a time -----
    float A[64];
#pragma unroll
    for (int c = 0; c < 64; ++c) A[c] = 0.0f;
    float sq_own = 0.0f;
#pragma unroll
    for (int j = 0; j < 30; ++j) {
        int cj = cs[i * MNB + j];                     // wave-uniform (s_load)
        float scl = __expf(-0.5f * (float)(j + 1) * et2);
        float xj = 0.0f;
        if (cj >= 0) xj = respT[cj * 64 + lane] * scl;  // coalesced 256B row
        sq_own = fmaf(xj, xj, sq_own);
#pragma unroll
        for (int c = 0; c < 64; ++c)
            A[c] = fmaf(xj, rl(xj, c), A[c]);         // v * s fma
    }

    // ---- transform: A[c] = (lin + sigma^2*matern)/nug + I ---------------
    const float mc = 1.7320508075688772f;  // sqrt(3)
#pragma unroll
    for (int c = 0; c < 64; ++c) {
        float acc = A[c];
        float dc = rl(sq_own, c);
        float d2 = fmaxf((sq_own + dc - 2.0f * acc) * inv_len2, 1e-12f);
        float d  = sqrtf(d2);
        float t  = mc * d;
        float mat = (1.0f + t) * __expf(-t);
        A[c] = (acc + sig2 * mat) * inv_nug + ((c == lane) ? 1.0f : 0.0f);
    }

    // ---- Cholesky: right-looking, symmetric full-row update -------------
    float logdet_acc = 0.0f;
    float my_dinv = 0.0f;
#pragma unroll
    for (int k = 0; k < 64; ++k) {
        float p   = rl(A[k], k);                      // pivot (uniform)
        float inv = __frsqrt_rn(p);
        logdet_acc += __logf(p);                      // uniform accumulate
        float myL = A[k] * inv;                       // L[lane][k] (lane>=k)
        A[k] = myL;
        my_dinv = (lane == k) ? inv : my_dinv;
#pragma unroll
        for (int c = k + 1; c < 64; ++c)
            A[c] = fmaf(-myL, rl(myL, c), A[c]);      // A[c] -= L[lane][k]*L[c][k]
    }

    // ---- forward solve L y~ = y; q = sum y~^2 accumulates uniformly -----
    float s = y_own;
    float q = 0.0f;
#pragma unroll
    for (int j = 0; j < 64; ++j) {
        float t  = s * my_dinv;                       // lane j holds y~[j]
        float yj = rl(t, j);                          // SGPR, uniform
        q  = fmaf(yj, yj, q);                         // uniform across lanes
        s  = fmaf(-A[j], yj, s);
    }

    // ---- log-likelihood (uniform; lane 0 commits) -----------------------
    float logdet = 0.5f * logdet_acc;
    const float alpha      = 2.0625f;                  // 1/16 + 2 (NUG_MULT=4)
    const float alpha_post = 34.0625f;                 // alpha + n/2
    float beta      = nug * (alpha - 1.0f);
    float beta_post = fmaf(0.5f, q, beta);
    float loglik = -logdet + alpha * __logf(beta) - alpha_post * __logf(beta_post)
                   + lgammaf(alpha_post) - lgammaf(alpha);

    if (lane == 0) sh_part[wave] = loglik;
    __syncthreads();
    if (threadIdx.x == 0) {
        float tsum = sh_part[0] + sh_part[1] + sh_part[2] + sh_part[3];
        atomicAdd(out, -tsum * (1.0f / (float)NLOC));
    }
}

// ---------------------------------------------------------------------------
extern "C" void kernel_launch(void* const* d_in, const int* in_sizes, int n_in,
                              void* d_out, int out_size, void* d_ws, size_t ws_size,
                              hipStream_t stream) {
    const float* locs  = (const float*)d_in[0];
    const float* resp  = (const float*)d_in[1];
    const int*   cset  = (const int*)d_in[2];
    const float* theta = (const float*)d_in[3];
    float* out   = (float*)d_out;
    float* respT = (float*)d_ws;                      // 20000*64*4 = 5.12 MB

    prep_transpose<<<(NLOC + 63) / 64, 256, 0, stream>>>(resp, respT, out);
    vecchia_main<<<NLOC / 4, 256, 0, stream>>>(locs, respT, cset, theta, out);
}